// Round 4
// baseline (96.341 us; speedup 1.0000x reference)
//
#include <hip/hip_runtime.h>

// LocallyConnected2d: x(16,3,128,128) f32, W(61,61,64,3,8,8) f32, bias(64,61,61) f32
// out(16,1,488,488) f32; stride 2, kernel 8, no pad; pixel-shuffle r=8 epilogue.
//
// R3: persistent double-buffered stream, 512 threads (8 waves = 2/SIMD; fixes
// R2's 1-wave/SIMD latency exposure). Wave = (batch-quad bq, K-half ks);
// lane = (oc-quad q, K-quarter kh) -> thread owns acc[4oc][4b] over K/8.
// W coalesced via global_load_lds(16B) into XOR-swizzled LDS (pre-swizzled
// source), x via global_load_lds(4B). Counted s_waitcnt vmcnt(12) keeps next
// tile's 12 loads/wave in flight across the barrier. K-combine: shfl_xor
// (kh) + 4KB LDS scratch exchange between ks-pairs (double-buffered).

namespace {
constexpr int NHW  = 61 * 61;       // 3721
constexpr int Kd   = 192;           // 3*8*8
constexpr int OC   = 64;
constexpr int XB   = 3 * 128 * 128;
constexpr int XCC  = 128 * 128;
constexpr int OSTR = 488 * 488;
constexpr int GRID = 256;

__device__ __forceinline__ int swz(int oc) { return (oc ^ (oc >> 3)) & 7; }
}

__global__ __launch_bounds__(512, 2) void lc2d_kernel(
    const float* __restrict__ xg,   // [16][3][128][128]
    const float* __restrict__ wg,   // [61][61][64][3][8][8]
    const float* __restrict__ bg,   // [64][61][61]
    float* __restrict__ og)         // [16][488][488]
{
    __shared__ float4 wl[2][OC * 48];               // 96 KB, swizzled rows
    __shared__ __align__(16) float xl[2][16 * Kd];  // 24 KB, linear [b][k]
    __shared__ float4 sc[2][4][64];                 // 8 KB ks-combine scratch

    const int bid  = blockIdx.x;
    const int t    = threadIdx.x;
    const int lane = t & 63;
    const int wv   = t >> 6;                        // 8 waves
    const int nt   = 14 + (bid < (NHW - 14 * GRID));

    const int q  = lane & 15;   // oc quad
    const int kh = lane >> 4;   // K quarter (within half)
    const int ks = wv & 1;      // K half
    const int bq = wv >> 1;     // batch quad

    // per-tile staging: 6x W(16B/lane = 1KB) + 6x x(4B/lane = 256B) per wave
    auto issue_tile = [&](int hw, int p) {
        const float* wbase = wg + (size_t)hw * (OC * Kd);
        #pragma unroll
        for (int ci = 0; ci < 6; ++ci) {
            const int s   = wv * 384 + ci * 64 + lane;   // float4 slot 0..3071
            const int ocs = s / 48;
            const int t4  = s - ocs * 48;
            const int k4  = t4 ^ swz(ocs);               // pre-swizzled source
            __builtin_amdgcn_global_load_lds(
                (const __attribute__((address_space(1))) void*)(wbase + (ocs * 48 + k4) * 4),
                (__attribute__((address_space(3))) void*)&wl[p][wv * 384 + ci * 64],
                16, 0, 0);
        }
        const int hh = hw / 61;
        const int ww = hw - hh * 61;
        const float* xb = xg + (hh * 2) * 128 + (ww * 2);
        #pragma unroll
        for (int ci = 0; ci < 6; ++ci) {
            const int g  = (wv * 6 + ci) * 64 + lane;    // float slot 0..3071
            const int b  = g / 192;
            const int r  = g - b * 192;
            const int c  = r >> 6;
            const int r2 = r & 63;
            const int ii = r2 >> 3;
            const int cl = r2 & 7;
            __builtin_amdgcn_global_load_lds(
                (const __attribute__((address_space(1))) void*)(xb + b * XB + c * XCC + ii * 128 + cl),
                (__attribute__((address_space(3))) void*)&xl[p][(wv * 6 + ci) * 64],
                4, 0, 0);
        }
    };

    issue_tile(bid, 0);   // prologue

    int p = 0;
    for (int i = 0; i < nt; ++i) {
        const int hw = bid + i * GRID;
        const int h  = hw / 61;
        const int w  = hw - h * 61;

        // bias BEFORE prefetch issue (FIFO: retired by the vmcnt(12) wait)
        float bz[4];
        #pragma unroll
        for (int j = 0; j < 4; ++j) bz[j] = bg[(q * 4 + j) * NHW + hw];
        asm volatile("" ::: "memory");

        if (i + 1 < nt) {
            issue_tile(bid + (i + 1) * GRID, p ^ 1);
            asm volatile("s_waitcnt vmcnt(12)" ::: "memory");  // tile i landed
        } else {
            asm volatile("s_waitcnt vmcnt(0)" ::: "memory");
        }
        __builtin_amdgcn_s_barrier();
        __builtin_amdgcn_sched_barrier(0);

        const float4* wlp = &wl[p][0];
        const float*  xlp = &xl[p][0];
        const int kbase = (ks * 4 + kh) * 6;   // float4 units (K/8 slice)

        float acc[4][4];   // [j(oc)][bb(batch in quad)]
        #pragma unroll
        for (int j = 0; j < 4; ++j)
            #pragma unroll
            for (int bb = 0; bb < 4; ++bb) acc[j][bb] = 0.f;

        #pragma unroll
        for (int kk = 0; kk < 6; ++kk) {
            float4 wv4[4];
            #pragma unroll
            for (int j = 0; j < 4; ++j) {
                const int oc = q * 4 + j;
                wv4[j] = wlp[oc * 48 + ((kbase + kk) ^ swz(oc))];
            }
            #pragma unroll
            for (int bb = 0; bb < 4; ++bb) {
                const float4 xv = *reinterpret_cast<const float4*>(
                    &xlp[(bq * 4 + bb) * Kd + (kbase + kk) * 4]);
                #pragma unroll
                for (int j = 0; j < 4; ++j) {
                    acc[j][bb] = fmaf(wv4[j].x, xv.x, acc[j][bb]);
                    acc[j][bb] = fmaf(wv4[j].y, xv.y, acc[j][bb]);
                    acc[j][bb] = fmaf(wv4[j].z, xv.z, acc[j][bb]);
                    acc[j][bb] = fmaf(wv4[j].w, xv.w, acc[j][bb]);
                }
            }
        }

        // ---- intra-wave K combine over kh (lanes xor 16/32)
        #pragma unroll
        for (int j = 0; j < 4; ++j)
            #pragma unroll
            for (int bb = 0; bb < 4; ++bb) {
                acc[j][bb] += __shfl_xor(acc[j][bb], 16);
                acc[j][bb] += __shfl_xor(acc[j][bb], 32);
            }

        // select bb = kh column with static indexing (no runtime array index)
        float colj[4];
        #pragma unroll
        for (int j = 0; j < 4; ++j) {
            float v = acc[j][0];
            v = (kh == 1) ? acc[j][1] : v;
            v = (kh == 2) ? acc[j][2] : v;
            v = (kh == 3) ? acc[j][3] : v;
            colj[j] = v;
        }

        // ---- cross-wave ks combine via double-buffered scratch
        const int sp = i & 1;
        if (ks == 1) {
            float4 o;
            o.x = colj[0]; o.y = colj[1]; o.z = colj[2]; o.w = colj[3];
            sc[sp][bq][lane] = o;
        }
        __builtin_amdgcn_sched_barrier(0);
        asm volatile("s_waitcnt lgkmcnt(0)" ::: "memory");
        __builtin_amdgcn_s_barrier();      // releases buf[p] + publishes scratch
        __builtin_amdgcn_sched_barrier(0);

        if (ks == 0) {
            const float4 o = sc[sp][bq][lane];
            const int b    = bq * 4 + kh;
            const int orow = h * 8 + (q >> 1);
            const int ocol = w * 8 + (q & 1) * 4;
            float4 ov;
            ov.x = colj[0] + o.x + bz[0];
            ov.y = colj[1] + o.y + bz[1];
            ov.z = colj[2] + o.z + bz[2];
            ov.w = colj[3] + o.w + bz[3];
            *reinterpret_cast<float4*>(og + (size_t)b * OSTR + orow * 488 + ocol) = ov;
        }

        p ^= 1;
    }
}

extern "C" void kernel_launch(void* const* d_in, const int* in_sizes, int n_in,
                              void* d_out, int out_size, void* d_ws, size_t ws_size,
                              hipStream_t stream) {
    const float* x    = (const float*)d_in[0];
    const float* W    = (const float*)d_in[1];
    const float* bias = (const float*)d_in[2];
    float* out        = (float*)d_out;
    lc2d_kernel<<<dim3(GRID), dim3(512), 0, stream>>>(x, W, bias, out);
}

// Round 5
// 66.065 us; speedup vs baseline: 1.4583x; 1.4583x over previous
//
#include <hip/hip_runtime.h>

// LocallyConnected2d: x(16,3,128,128) f32, W(61,61,64,3,8,8) f32, bias(64,61,61) f32
// out(16,1,488,488) f32; stride 2, kernel 8, no pad; pixel-shuffle r=8 epilogue.
//
// R4: back to the simple serial structure (R1, best so far) but with 2 blocks
// per hw (32 ocs each): LDS 36 KB -> 4 blocks/CU, 16 waves/CU. Cross-block TLP
// does the load/compute overlap that R2/R3's 1-block/CU pipelines could not.
// Mapping: lane=(q 0..7 oc-quad, kh 0..7 K-eighth), wave=batch-quad; thread
// owns acc[4oc][4b] over K/8 = 6 float4. W LDS rows rotation-swizzled
// (s4=(k4+q)%48, bijective, uniform banks) via pre-rotated global source.
// K-combine: 3-level shfl_xor (8/16/32); kh<4 lanes store batch bq*4+kh.

namespace {
constexpr int NHW  = 61 * 61;       // 3721
constexpr int Kd   = 192;           // 3*8*8
constexpr int XB   = 3 * 128 * 128;
constexpr int XCC  = 128 * 128;
constexpr int OSTR = 488 * 488;
}

__global__ __launch_bounds__(256, 4) void lc2d_kernel(
    const float* __restrict__ xg,   // [16][3][128][128]
    const float* __restrict__ wg,   // [61][61][64][3][8][8]
    const float* __restrict__ bg,   // [64][61][61]
    float* __restrict__ og)         // [16][488][488]
{
    __shared__ float4 wl[32 * 48];                 // 24 KB, rotation-swizzled rows
    __shared__ __align__(16) float xl[16 * Kd];    // 12 KB, linear [b][k]

    const int bid  = blockIdx.x;
    const int hw   = bid >> 1;
    const int half = bid & 1;      // which 32-oc half
    const int h    = hw / 61;
    const int w    = hw - h * 61;
    const int t    = threadIdx.x;
    const int lane = t & 63;
    const int wv   = t >> 6;

    // ---- W staging (24 KB): coalesced global_load_lds(16B), pre-rotated src
    // LDS slot (ocl, t4) holds W[ocl][k4] with k4 = (t4 - (ocl>>2)) mod 48.
    {
        const float* wbase = wg + (size_t)hw * (64 * Kd) + half * (32 * Kd);
        #pragma unroll
        for (int ci = 0; ci < 6; ++ci) {
            const int s   = wv * 384 + ci * 64 + lane;   // f4 slot 0..1535
            const int ocl = s / 48;
            const int t4  = s - ocl * 48;
            int k4 = t4 - (ocl >> 2);
            if (k4 < 0) k4 += 48;
            __builtin_amdgcn_global_load_lds(
                (const __attribute__((address_space(1))) void*)(wbase + (ocl * 48 + k4) * 4),
                (__attribute__((address_space(3))) void*)&wl[wv * 384 + ci * 64],
                16, 0, 0);
        }
    }
    // ---- x staging (12 KB): manual float2 (validated R0/R1 mapping)
    {
        const float* xbase = xg + (h * 2) * 128 + (w * 2);
        #pragma unroll
        for (int ci = 0; ci < 6; ++ci) {
            const int f  = ci * 256 + t;     // float2 slot 0..1535
            const int b  = f / 96;
            const int r  = f - b * 96;
            const int c  = r >> 5;
            const int r2 = r & 31;
            const int i  = r2 >> 2;
            const int j0 = (r2 & 3) * 2;
            const float2 v = *reinterpret_cast<const float2*>(
                xbase + b * XB + c * XCC + i * 128 + j0);
            *reinterpret_cast<float2*>(&xl[b * Kd + c * 64 + i * 8 + j0]) = v;
        }
    }

    const int q  = lane & 7;    // oc quad within the 32-oc half
    const int kh = lane >> 3;   // K eighth
    const int bq = wv;          // batch quad

    // bias for my 4 ocs (tiny, L2-resident; issued before the sync)
    float bz[4];
    #pragma unroll
    for (int j = 0; j < 4; ++j)
        bz[j] = bg[(half * 32 + q * 4 + j) * NHW + hw];

    __syncthreads();

    float acc[4][4];   // [j(oc)][bb(batch in quad)]
    #pragma unroll
    for (int j = 0; j < 4; ++j)
        #pragma unroll
        for (int bb = 0; bb < 4; ++bb) acc[j][bb] = 0.f;

    const int kb = kh * 6;   // f4 units: my K/8 slice

    #pragma unroll
    for (int kk = 0; kk < 6; ++kk) {
        int s4 = kb + kk + q;            // rotation swizzle (same for all j)
        if (s4 >= 48) s4 -= 48;
        float4 wv4[4];
        #pragma unroll
        for (int j = 0; j < 4; ++j)
            wv4[j] = wl[(q * 4 + j) * 48 + s4];
        #pragma unroll
        for (int bb = 0; bb < 4; ++bb) {
            const float4 xv = *reinterpret_cast<const float4*>(
                &xl[(bq * 4 + bb) * Kd + (kb + kk) * 4]);
            #pragma unroll
            for (int j = 0; j < 4; ++j) {
                acc[j][bb] = fmaf(wv4[j].x, xv.x, acc[j][bb]);
                acc[j][bb] = fmaf(wv4[j].y, xv.y, acc[j][bb]);
                acc[j][bb] = fmaf(wv4[j].z, xv.z, acc[j][bb]);
                acc[j][bb] = fmaf(wv4[j].w, xv.w, acc[j][bb]);
            }
        }
    }

    // ---- K-combine over kh (lane bits 3,4,5 -> xor 8/16/32)
    #pragma unroll
    for (int j = 0; j < 4; ++j)
        #pragma unroll
        for (int bb = 0; bb < 4; ++bb) {
            acc[j][bb] += __shfl_xor(acc[j][bb], 8);
            acc[j][bb] += __shfl_xor(acc[j][bb], 16);
            acc[j][bb] += __shfl_xor(acc[j][bb], 32);
        }

    // static select of batch column kh (no runtime array index -> no scratch)
    float colj[4];
    #pragma unroll
    for (int j = 0; j < 4; ++j) {
        float v = acc[j][0];
        v = (kh == 1) ? acc[j][1] : v;
        v = (kh == 2) ? acc[j][2] : v;
        v = (kh == 3) ? acc[j][3] : v;
        colj[j] = v;
    }

    // ---- store: kh<4 lanes store batch bq*4+kh as float4 over the oc quad
    if (kh < 4) {
        const int b    = bq * 4 + kh;
        const int orow = h * 8 + half * 4 + (q >> 1);
        const int ocol = w * 8 + (q & 1) * 4;
        float4 ov;
        ov.x = colj[0] + bz[0];
        ov.y = colj[1] + bz[1];
        ov.z = colj[2] + bz[2];
        ov.w = colj[3] + bz[3];
        *reinterpret_cast<float4*>(og + (size_t)b * OSTR + orow * 488 + ocol) = ov;
    }
}

extern "C" void kernel_launch(void* const* d_in, const int* in_sizes, int n_in,
                              void* d_out, int out_size, void* d_ws, size_t ws_size,
                              hipStream_t stream) {
    const float* x    = (const float*)d_in[0];
    const float* W    = (const float*)d_in[1];
    const float* bias = (const float*)d_in[2];
    float* out        = (float*)d_out;
    lc2d_kernel<<<dim3(NHW * 2), dim3(256), 0, stream>>>(x, W, bias, out);
}